// Round 3
// baseline (96.961 us; speedup 1.0000x reference)
//
#include <hip/hip_runtime.h>
#include <hip/hip_bf16.h>
#include <cstdint>

// HopfieldLayer: out = attn(attn(R,Y,Y), Y, Y), H=8 heads, E=64, scale 1/8.
// R3: S-split x2 inside the wg (wave-pairs own half the KV stream each; merged
// at the end via LDS) -> grid 1024, 4 blocks/CU, 50% occupancy cap. Defer-max
// (T13, THR=8) skips the alpha-rescale on most tiles. Double-buffered KV +
// async reg staging kept from R2.

typedef __attribute__((ext_vector_type(8))) short bf16x8;
typedef __attribute__((ext_vector_type(4))) short short4v;
typedef __attribute__((ext_vector_type(4))) float f32x4;

constexpr int B_ = 2, L_ = 2048, S_ = 2048, H_ = 8, E_ = 64, DM_ = 512;
constexpr int NTH_ = 16; // KV tiles per S-half (32 total / 2)
constexpr float SCALE2 = 0.18033688011112042f; // (1/sqrt(64)) * log2(e)

__device__ __forceinline__ ushort f2bf(float a) {
  uint32_t u = __builtin_bit_cast(uint32_t, a);
  return (ushort)((u + 0x7fffu + ((u >> 16) & 1u)) >> 16); // RNE, finite inputs
}
__device__ __forceinline__ uint32_t bf16pack(float a, float b) {
  uint32_t ua = __builtin_bit_cast(uint32_t, a);
  uint32_t ub = __builtin_bit_cast(uint32_t, b);
  ua = (ua + 0x7fffu + ((ua >> 16) & 1u)) >> 16;
  ub = (ub + 0x7fffu + ((ub >> 16) & 1u)) >> 16;
  return (ua & 0xffffu) | (ub << 16);
}

__global__ void cvt_kernel(const float* __restrict__ in, ushort* __restrict__ out,
                           int n4, float mul) {
  int i = blockIdx.x * 256 + threadIdx.x;
  if (i >= n4) return;
  float4 v = reinterpret_cast<const float4*>(in)[i];
  ushort4 o;
  o.x = f2bf(v.x * mul); o.y = f2bf(v.y * mul);
  o.z = f2bf(v.z * mul); o.w = f2bf(v.w * mul);
  reinterpret_cast<ushort4*>(out)[i] = o;
}

// KV LDS tile: 64s x 64e bf16, sub-tiled for tr-reads:
//   idx(s,e) = block*64 + (s&3)*16 + (e&15),
//   block = (((s>>2)&1)*4 + (e>>4))*8 + (s>>3)
// P LDS (per wave, 512 u32): u32 idx = ((nt*16+qi)*4+g)*2+w
template <bool OUT_F32>
__global__ __launch_bounds__(256, 4) void attn_kernel(
    const ushort* __restrict__ Qb,  // bf16 [B,L,512], pre-scaled by SCALE2
    const ushort* __restrict__ Yb,  // bf16 [B,S,512]
    float* __restrict__ outF, ushort* __restrict__ outB) {
  __shared__ ushort Vsub[2][2][4096]; // [s-half pair][double-buf] 32 KB
  __shared__ uint32_t Plds[4][512];   // 8 KB, wave-private P^T staging

  const int tid = threadIdx.x;
  const int lane = tid & 63;
  const int wid = tid >> 6;
  const int g = lane >> 4;   // 16-lane group 0..3
  const int qi = lane & 15;  // this lane's q column
  const int pair = wid >> 1; // S-half this wave works on
  const int qs = wid & 1;    // q sub-tile (16 rows) within the wg's 32

  const int wg = blockIdx.x;
  const int qt = wg & 63;         // L/32 = 64 q-tiles
  const int h = (wg >> 6) & 7;
  const int b = wg >> 9;

  const int qglob = qt * 32 + qs * 16 + qi;
  const size_t qrow_off = (size_t)(b * L_ + qglob) * DM_ + h * E_;

  // Q B-fragments (lane holds Q[qi][8 contiguous e]) — row reads
  bf16x8 qf0 = *reinterpret_cast<const bf16x8*>(Qb + qrow_off + g * 8);
  bf16x8 qf1 = *reinterpret_cast<const bf16x8*>(Qb + qrow_off + 32 + g * 8);

  f32x4 oacc[4];
#pragma unroll
  for (int et = 0; et < 4; ++et) oacc[et] = f32x4{0.f, 0.f, 0.f, 0.f};
  float m = -1e30f, lsum = 0.f;

  const size_t ybase = (size_t)(b * S_) * DM_ + h * E_;

  // staging geometry: wave-pair (128 threads) stages its own 8 KB tile;
  // thread chunk it: cidx = it*128 + ptid, 16 B each
  const int ptid = tid & 127;
  const int cc = ptid & 7;              // e-chunk (8 bf16)
  int lidx[4];
  const ushort* gsrc[4];
#pragma unroll
  for (int it = 0; it < 4; ++it) {
    int r = it * 16 + (ptid >> 3);      // s-row 0..63
    lidx[it] = ((((r >> 2) & 1) * 4 + (cc >> 1)) * 8 + (r >> 3)) * 64 +
               (r & 3) * 16 + (cc & 1) * 8;
    gsrc[it] = Yb + ybase + (size_t)(pair * 1024 + r) * DM_ + cc * 8;
  }

  // ---- prologue: stage tile 0 of this S-half into buffer 0
#pragma unroll
  for (int it = 0; it < 4; ++it)
    *reinterpret_cast<uint4*>(&Vsub[pair][0][lidx[it]]) =
        *reinterpret_cast<const uint4*>(gsrc[it]);
  __syncthreads();

  const uint32_t vb0 = (uint32_t)(uintptr_t)(&Vsub[pair][0][0]);
  int cur = 0;

  for (int t = 0; t < NTH_; ++t) {
    // ---- issue next tile's global loads early
    const int tn = (t + 1 < NTH_) ? t + 1 : t;
    uint4 pf[4];
#pragma unroll
    for (int it = 0; it < 4; ++it)
      pf[it] = *reinterpret_cast<const uint4*>(gsrc[it] + (size_t)tn * 64 * DM_);

    const ushort* Vc = &Vsub[pair][cur][0];
    const uint32_t vbc = vb0 + (uint32_t)(cur * 8192);

    // ---- S^T = mfma(A=K, B=Q): D[s-in-16][q], row=4g+reg, col=qi
    f32x4 st[4];
#pragma unroll
    for (int nt = 0; nt < 4; ++nt) {
      f32x4 acc = f32x4{0.f, 0.f, 0.f, 0.f};
#pragma unroll
      for (int eck = 0; eck < 2; ++eck) {
        int s = nt * 16 + qi;
        int idx = ((((s >> 2) & 1) * 4 + (eck * 2 + (g >> 1))) * 8 + (s >> 3)) * 64 +
                  (s & 3) * 16 + (g & 1) * 8;
        bf16x8 ak = *reinterpret_cast<const bf16x8*>(&Vc[idx]);
        acc = __builtin_amdgcn_mfma_f32_16x16x32_bf16(ak, eck ? qf1 : qf0, acc, 0, 0, 0);
      }
      st[nt] = acc;
    }

    // ---- online softmax with defer-max (T13, THR=8); exp2 domain
    float tm = -1e30f;
#pragma unroll
    for (int nt = 0; nt < 4; ++nt)
#pragma unroll
      for (int r = 0; r < 4; ++r) tm = fmaxf(tm, st[nt][r]);
    tm = fmaxf(tm, __shfl_xor(tm, 16));
    tm = fmaxf(tm, __shfl_xor(tm, 32));
    if (__any(tm > m + 8.f)) {
      float mnew = fmaxf(m, tm);
      float alpha = __builtin_amdgcn_exp2f(m - mnew);
      m = mnew;
      lsum *= alpha;
#pragma unroll
      for (int et = 0; et < 4; ++et) oacc[et] *= alpha;
    }
    float p[16];
#pragma unroll
    for (int i = 0; i < 16; ++i) {
      p[i] = __builtin_amdgcn_exp2f(st[i >> 2][i & 3] - m); // bounded by 2^8
      lsum += p[i];
    }

    // ---- P^T to wave-local LDS: [nt][qi][g][w]
#pragma unroll
    for (int nt = 0; nt < 4; ++nt) {
      uint2 w;
      w.x = bf16pack(p[nt * 4 + 0], p[nt * 4 + 1]);
      w.y = bf16pack(p[nt * 4 + 2], p[nt * 4 + 3]);
      *reinterpret_cast<uint2*>(&Plds[wid][((nt * 16 + qi) * 4 + g) * 2]) = w;
    }

    // ---- PV: O^T[e][q] += mfma(A=V^T, B=P^T) over 2 k-chunks of 32 s
#pragma unroll
    for (int ck = 0; ck < 2; ++ck) {
      uint4 pw = *reinterpret_cast<const uint4*>(
          &Plds[wid][(((2 * ck + (g >> 1)) * 16 + qi) * 4 + 2 * (g & 1)) * 2]);
      bf16x8 pfrag = __builtin_bit_cast(bf16x8, pw);

      short4v tr[4][2];
#pragma unroll
      for (int et = 0; et < 4; ++et)
#pragma unroll
        for (int pb = 0; pb < 2; ++pb) {
          uint32_t addr = vbc + (uint32_t)((((pb * 4 + et) * 8) + 4 * ck) * 128) + 8u * (uint32_t)lane;
          asm volatile("ds_read_b64_tr_b16 %0, %1" : "=v"(tr[et][pb]) : "v"(addr));
        }
      asm volatile("s_waitcnt lgkmcnt(0)" ::: "memory");
      __builtin_amdgcn_sched_barrier(0); // rule #18

#pragma unroll
      for (int et = 0; et < 4; ++et) {
        short4v lo = tr[et][0], hi = tr[et][1];
        bf16x8 vf;
        vf[0] = lo[0]; vf[1] = lo[1]; vf[2] = lo[2]; vf[3] = lo[3];
        vf[4] = hi[0]; vf[5] = hi[1]; vf[6] = hi[2]; vf[7] = hi[3];
        oacc[et] = __builtin_amdgcn_mfma_f32_16x16x32_bf16(vf, pfrag, oacc[et], 0, 0, 0);
      }
    }

    // ---- write next tile into the other buffer; single barrier per tile
    if (t + 1 < NTH_) {
#pragma unroll
      for (int it = 0; it < 4; ++it)
        *reinterpret_cast<uint4*>(&Vsub[pair][cur ^ 1][lidx[it]]) = pf[it];
      __syncthreads();
      cur ^= 1;
    }
  }

  // ---- per-wave l reduction (across g for each qi)
  lsum += __shfl_xor(lsum, 16);
  lsum += __shfl_xor(lsum, 32);

  // ---- merge the two S-halves (wave w in {0,1} with wave w+2) via LDS
  __syncthreads(); // all KV reads done; Vsub reusable as merge scratch
  float* mrgO = (float*)&Vsub[0][0][0];   // [pw][et][lane][4] = 2048 f32
  float* mrgML = mrgO + 2048;             // [pw][{m,l}][lane] = 256 f32

  if (wid >= 2) {
    const int pw = wid - 2;
#pragma unroll
    for (int et = 0; et < 4; ++et)
      *reinterpret_cast<f32x4*>(&mrgO[((pw * 4 + et) * 64 + lane) * 4]) = oacc[et];
    mrgML[pw * 128 + lane] = m;
    mrgML[pw * 128 + 64 + lane] = lsum;
  }
  __syncthreads();
  if (wid < 2) {
    const int pw = wid;
    float m1 = mrgML[pw * 128 + lane];
    float l1 = mrgML[pw * 128 + 64 + lane];
    float M = fmaxf(m, m1);
    float f0 = __builtin_amdgcn_exp2f(m - M);
    float f1 = __builtin_amdgcn_exp2f(m1 - M);
    float inv = 1.0f / (lsum * f0 + l1 * f1);
#pragma unroll
    for (int et = 0; et < 4; ++et) {
      f32x4 O1 = *reinterpret_cast<const f32x4*>(&mrgO[((pw * 4 + et) * 64 + lane) * 4]);
#pragma unroll
      for (int r = 0; r < 4; ++r) {
        int e = et * 16 + 4 * g + r;
        float val = (oacc[et][r] * f0 + O1[r] * f1) * inv;
        if constexpr (OUT_F32) outF[qrow_off + e] = val;
        else outB[qrow_off + e] = f2bf(val * SCALE2); // pre-scale for step-2 Q
      }
    }
  }
}

extern "C" void kernel_launch(void* const* d_in, const int* in_sizes, int n_in,
                              void* d_out, int out_size, void* d_ws, size_t ws_size,
                              hipStream_t stream) {
  const float* R = (const float*)d_in[0];
  const float* Y = (const float*)d_in[1];
  float* outF = (float*)d_out;

  constexpr int NE = B_ * L_ * DM_; // 2,097,152 elements per tensor
  ushort* Rb = (ushort*)d_ws;
  ushort* Yb = Rb + NE;
  ushort* q1 = Yb + NE;

  const int n4 = NE / 4;
  cvt_kernel<<<dim3((n4 + 255) / 256), 256, 0, stream>>>(R, Rb, n4, SCALE2);
  cvt_kernel<<<dim3((n4 + 255) / 256), 256, 0, stream>>>(Y, Yb, n4, 1.0f);

  const int ngrid = B_ * H_ * (L_ / 32); // 1024 workgroups = 4 blocks/CU
  attn_kernel<false><<<dim3(ngrid), 256, 0, stream>>>(Rb, Yb, nullptr, q1);
  attn_kernel<true><<<dim3(ngrid), 256, 0, stream>>>(q1, Yb, outF, nullptr);
}